// Round 1
// 478.166 us; speedup vs baseline: 1.0041x; 1.0041x over previous
//
#include <hip/hip_runtime.h>
#include <math.h>

#define NN 50000
#define NE 800000
#define DF 128
#define NPART 8
#define PART_SZ (NN / NPART)        // 6250, exact
#define STG_CAP 108544              // part segment: 100000 expected + slack
#define BIN_BLOCKS 512
#define BUCK_CAP 512
#define CHUNKS 16                   // chunks per part
#define CH_W 391                    // ceil(PART_SZ / CHUNKS); last chunk = 385
#define SUB_CAP 7680                // chunk mean 6256 edges, +18 sigma
#define SB_CAP 448                  // subbin bucket capacity
#define SB_TH 192                   // subbin flush threshold
#define SUBBIN_BLOCKS 512           // 16 segments x 32 slices
#define GEMM_TILE_ROWS 64           // rows per block in MFMA gemm (4 waves x 16)

__device__ __forceinline__ unsigned short f2bf(float f) {  // round-to-nearest-even
    unsigned u = __float_as_uint(f);
    return (unsigned short)((u + 0x7FFF + ((u >> 16) & 1)) >> 16);
}
#define BF2F(u) __uint_as_float(((unsigned)(u)) << 16)

typedef __attribute__((ext_vector_type(8))) short bf16x8;
typedef __attribute__((ext_vector_type(4))) float f32x4;

// ---------------- phase 1: bin edges by dst-part into staging (r5-proven) ----------------
__global__ __launch_bounds__(256) void bin_kernel(const int* __restrict__ src1, const int* __restrict__ dst1,
                                                  const int* __restrict__ src2, const int* __restrict__ dst2,
                                                  int2* __restrict__ stg, int* __restrict__ stgcnt) {
    __shared__ int2 buck[NPART][BUCK_CAP];   // 32 KB
    __shared__ int bcnt[NPART];
    __shared__ int wbase[4][NPART];
    __shared__ int gbase[NPART];
    const int t = threadIdx.x, lane = t & 63, w = t >> 6;
    const int g = (blockIdx.x >= BIN_BLOCKS / 2) ? 1 : 0;
    const int bid = blockIdx.x - g * (BIN_BLOCKS / 2);
    const int nb = BIN_BLOCKS / 2;
    const int* __restrict__ srcv = g ? src2 : src1;
    const int* __restrict__ dstv = g ? dst2 : dst1;
    int2* __restrict__ stg_g = stg + (size_t)g * NPART * STG_CAP;
    int* __restrict__ cnt_g = stgcnt + g * NPART;
    if (t < NPART) bcnt[t] = 0;
    __syncthreads();
    for (int base = bid * 256; base < NE; base += nb * 256) {
        const int e = base + t;
        const bool v = (e < NE);
        int d = 0, s = 0, p = -1;
        if (v) { d = dstv[e]; s = srcv[e]; p = d / PART_SZ; }
        int rank = 0;
        const unsigned long long lt = (1ull << lane) - 1ull;
        int wc[NPART];
        #pragma unroll
        for (int q = 0; q < NPART; q++) {
            unsigned long long m = __ballot(p == q);
            wc[q] = (int)__popcll(m);
            if (p == q) rank = (int)__popcll(m & lt);
        }
        if (lane < NPART) wbase[w][lane] = wc[lane];
        __syncthreads();
        if (t < NPART) {
            int b = bcnt[t];
            int c0 = wbase[0][t], c1 = wbase[1][t], c2 = wbase[2][t], c3 = wbase[3][t];
            wbase[0][t] = b; wbase[1][t] = b + c0;
            wbase[2][t] = b + c0 + c1; wbase[3][t] = b + c0 + c1 + c2;
            bcnt[t] = b + c0 + c1 + c2 + c3;
        }
        __syncthreads();
        if (v) buck[p][wbase[w][p] + rank] = make_int2(s, d);
        __syncthreads();
        const bool last = (base + nb * 256) >= NE;
        if (t < NPART) {
            int c = bcnt[t];
            gbase[t] = (c >= 256 || (last && c > 0)) ? atomicAdd(&cnt_g[t], c) : -1;
        }
        __syncthreads();
        #pragma unroll
        for (int q = 0; q < NPART; q++) {
            int gb = gbase[q];
            if (gb >= 0) {
                int c = bcnt[q];
                for (int i = t; i < c; i += 256)
                    stg_g[(size_t)q * STG_CAP + gb + i] = buck[q][i];
            }
        }
        __syncthreads();
        if (t < NPART && gbase[t] >= 0) bcnt[t] = 0;
    }
}

// ---------------- phase 2: sub-bin part segments into 16 chunk sub-segments ----------------
__global__ __launch_bounds__(256) void subbin_kernel(const int2* __restrict__ stg, const int* __restrict__ stgcnt,
                                                     int2* __restrict__ stg2, int* __restrict__ subcnt) {
    __shared__ int2 buck[CHUNKS][SB_CAP];   // 56 KB
    __shared__ int bcnt[CHUNKS];
    __shared__ int wbase[4][CHUNKS];
    __shared__ int gbase[CHUNKS];
    const int t = threadIdx.x, lane = t & 63, w = t >> 6;
    const int p = blockIdx.x & 7;
    const int g = (blockIdx.x >> 3) & 1;
    const int slice = blockIdx.x >> 4;               // 0..31
    const int nsl = SUBBIN_BLOCKS / 16;              // 32
    const int m = stgcnt[g * NPART + p];
    const int2* __restrict__ seg = stg + ((size_t)g * NPART + p) * STG_CAP;
    const int segi0 = g * 128 + p * CHUNKS;
    int* __restrict__ cnt_c = subcnt + segi0;
    int2* __restrict__ out = stg2 + (size_t)segi0 * SUB_CAP;
    const int plo = p * PART_SZ;
    if (t < CHUNKS) bcnt[t] = 0;
    __syncthreads();
    for (int base = slice * 256; base < m; base += nsl * 256) {
        const int e = base + t;
        const bool v = (e < m);
        int2 ed = make_int2(0, 0);
        int q = -1;
        if (v) { ed = seg[e]; q = (ed.y - plo) / CH_W; }
        int rank = 0;
        const unsigned long long lt = (1ull << lane) - 1ull;
        int wc[CHUNKS];
        #pragma unroll
        for (int qq = 0; qq < CHUNKS; qq++) {
            unsigned long long mm = __ballot(q == qq);
            wc[qq] = (int)__popcll(mm);
            if (q == qq) rank = (int)__popcll(mm & lt);
        }
        if (lane < CHUNKS) wbase[w][lane] = wc[lane];
        __syncthreads();
        if (t < CHUNKS) {
            int b = bcnt[t];
            int c0 = wbase[0][t], c1 = wbase[1][t], c2 = wbase[2][t], c3 = wbase[3][t];
            wbase[0][t] = b; wbase[1][t] = b + c0;
            wbase[2][t] = b + c0 + c1; wbase[3][t] = b + c0 + c1 + c2;
            bcnt[t] = b + c0 + c1 + c2 + c3;
        }
        __syncthreads();
        if (v) buck[q][wbase[w][q] + rank] = ed;
        __syncthreads();
        const bool last = (base + nsl * 256) >= m;
        if (t < CHUNKS) {
            int c = bcnt[t];
            gbase[t] = (c >= SB_TH || (last && c > 0)) ? atomicAdd(&cnt_c[t], c) : -1;
        }
        __syncthreads();
        #pragma unroll
        for (int qq = 0; qq < CHUNKS; qq++) {
            int gb = gbase[qq];
            if (gb >= 0) {
                int c = bcnt[qq];
                for (int i = t; i < c; i += 256)
                    if (gb + i < SUB_CAP)
                        out[(size_t)qq * SUB_CAP + gb + i] = buck[qq][i];
            }
        }
        __syncthreads();
        if (t < CHUNKS && gbase[t] >= 0) bcnt[t] = 0;
    }
}

// ---------------- phase 3: scan the 256 chunk counts -> chunk bases ----------------
__global__ __launch_bounds__(256) void chunkscan_kernel(const int* __restrict__ subcnt, int* __restrict__ cbase,
                                                        int* __restrict__ rp1, int* __restrict__ rp2) {
    __shared__ int wtot[4];
    const int t = threadIdx.x, lane = t & 63, w = t >> 6;
    int v = subcnt[t];
    int x = v;
    #pragma unroll
    for (int off = 1; off < 64; off <<= 1) { int y = __shfl_up(x, off); if (lane >= off) x += y; }
    if (lane == 63) wtot[w] = x;
    __syncthreads();
    int add = (w == 1) ? wtot[0] : ((w == 3) ? wtot[2] : 0);
    cbase[t] = x - v + add;
    if (t == 0) { rp1[NN] = NE; rp2[NN] = NE; }
}

// ---------------- phase 4: per-chunk degree hist + LDS scan -> rp + dinv ----------------
__global__ __launch_bounds__(256) void histrp_kernel(const int2* __restrict__ stg2, const int* __restrict__ subcnt,
                                                     const int* __restrict__ cbase,
                                                     int* __restrict__ rp1, float* __restrict__ dinv1,
                                                     int* __restrict__ rp2, float* __restrict__ dinv2) {
    __shared__ int deg[512];
    const int t = threadIdx.x;
    const int p = blockIdx.x & 7, c = (blockIdx.x >> 3) & 15, g = blockIdx.x >> 7;
    const int segi = g * 128 + p * CHUNKS + c;
    int m = subcnt[segi];
    if (m > SUB_CAP) m = SUB_CAP;
    const int2* __restrict__ seg = stg2 + (size_t)segi * SUB_CAP;
    int* __restrict__ rp = g ? rp2 : rp1;
    float* __restrict__ dinv = g ? dinv2 : dinv1;
    const int lo = p * PART_SZ + c * CH_W;
    int hi = lo + CH_W;
    const int pend = (p + 1) * PART_SZ;
    if (hi > pend) hi = pend;
    const int nw = hi - lo;
    deg[t] = 0; deg[t + 256] = 0;
    __syncthreads();
    for (int i = t; i < m; i += 256) atomicAdd(&deg[seg[i].y - lo], 1);
    __syncthreads();
    if (t < nw) dinv[lo + t] = rsqrtf((float)deg[t] + 1.0f);
    if (t + 256 < nw) dinv[lo + t + 256] = rsqrtf((float)deg[t + 256] + 1.0f);
    #pragma unroll
    for (int off = 1; off < 512; off <<= 1) {
        int v0 = (t >= off) ? deg[t - off] : 0;
        int v1 = (t + 256 >= off) ? deg[t + 256 - off] : 0;
        __syncthreads();
        deg[t] += v0; deg[t + 256] += v1;
        __syncthreads();
    }
    const int base = cbase[segi];
    if (t < nw) rp[lo + t] = base + (t ? deg[t - 1] : 0);
    if (t + 256 < nw) rp[lo + t + 256] = base + deg[t + 256 - 1];
}

// ---------------- phase 5: LDS-sorted placement from OWN sub-segment ----------------
__global__ __launch_bounds__(256) void place_kernel(const int2* __restrict__ stg2, const int* __restrict__ subcnt,
                                                    const int* __restrict__ rp1, const int* __restrict__ rp2,
                                                    const float* __restrict__ dinv1, const float* __restrict__ dinv2,
                                                    int2* __restrict__ pk1, int2* __restrict__ pk2) {
    __shared__ int2 sorted[SUB_CAP];    // 60 KB
    __shared__ int fill[CH_W];
    __shared__ int rps[CH_W + 1];
    const int t = threadIdx.x;
    const int p = blockIdx.x & 7, c = (blockIdx.x >> 3) & 15, g = blockIdx.x >> 7;
    const int segi = g * 128 + p * CHUNKS + c;
    int m = subcnt[segi];
    if (m > SUB_CAP) m = SUB_CAP;
    const int2* __restrict__ seg = stg2 + (size_t)segi * SUB_CAP;
    const int* __restrict__ rp = g ? rp2 : rp1;
    const float* __restrict__ dinv = g ? dinv2 : dinv1;
    int2* __restrict__ pk = g ? pk2 : pk1;
    const int lo = p * PART_SZ + c * CH_W;
    int hi = lo + CH_W;
    const int pend = (p + 1) * PART_SZ;
    if (hi > pend) hi = pend;
    const int nw = hi - lo;
    for (int i = t; i < nw; i += 256) { fill[i] = 0; rps[i] = rp[lo + i]; }
    if (t == 0) rps[nw] = rp[hi];
    __syncthreads();
    const int segbase = rps[0];
    const int total = rps[nw] - segbase;
    for (int i = t; i < m; i += 256) {
        int2 e = seg[i];
        int dl = e.y - lo;
        int lp = rps[dl] - segbase + atomicAdd(&fill[dl], 1);
        if (lp < SUB_CAP)
            sorted[lp] = make_int2(e.x, __float_as_int(dinv[e.x]));
    }
    __syncthreads();
    for (int i = t; i < total; i += 256)
        pk[segbase + i] = sorted[i];
}

// ---------------- W prep: W[k][n] fp32 -> W^T[n][k] bf16 hi/lo, all 4 layers ----------------
// hi = bf16_rne(w); lo = bf16_rne(w - hi). 3-product split gives ~fp32-accurate GEMM.
__global__ __launch_bounds__(256) void wprep_kernel(const float* __restrict__ W1, const float* __restrict__ W2,
                                                    const float* __restrict__ W3, const float* __restrict__ W4,
                                                    unsigned short* __restrict__ Wth, unsigned short* __restrict__ Wtl) {
    const int t = blockIdx.x * 256 + threadIdx.x;   // 0..65535
    const int layer = t >> 14;
    const int idx = t & 16383;
    const int nn = idx >> 7, kk = idx & 127;
    const float* __restrict__ W = layer == 0 ? W1 : layer == 1 ? W2 : layer == 2 ? W3 : W4;
    float v = W[kk * DF + nn];
    unsigned short h = f2bf(v);
    float rem = v - BF2F(h);
    Wth[t] = h;               // t == layer*16384 + nn*128 + kk  -> [layer][n][k]
    Wtl[t] = f2bf(rem);
}

// ---------------- H = X @ W via bf16x3-split MFMA (fp32-accurate) ----------------
// 4 waves x 16 rows = 64 rows/block, 128 cols. A-frag: m=lane&15, k=(lane>>4)*8+e.
// B-frag from W^T[n][k]: n=lane&15, k=(lane>>4)*8+e -> contiguous 16B load.
// D-frag: col=lane&15, row=(lane>>4)*4+reg (verified gfx950 layout).
__global__ __launch_bounds__(256) void gemm_mfma_kernel(const float* __restrict__ X,
                                                        const unsigned short* __restrict__ Wth,
                                                        const unsigned short* __restrict__ Wtl,
                                                        float* __restrict__ H, unsigned short* __restrict__ Hb, int n) {
    const int t = threadIdx.x;
    const int lane = t & 63, w = t >> 6;
    const int lm = lane & 15;      // A-row / B-col / D-col within 16x16 tile
    const int kg = lane >> 4;      // k subgroup 0..3
    const int row = blockIdx.x * GEMM_TILE_ROWS + w * 16 + lm;

    // load + split A fragments (read X once; hi/lo bf16 in registers)
    bf16x8 ah[4], al[4];
    #pragma unroll
    for (int ks = 0; ks < 4; ks++) {
        float4 x0 = make_float4(0.f, 0.f, 0.f, 0.f), x1 = x0;
        if (row < n) {
            const float* xp = X + (size_t)row * DF + ks * 32 + kg * 8;
            x0 = *(const float4*)xp;
            x1 = *(const float4*)(xp + 4);
        }
        float xv[8] = {x0.x, x0.y, x0.z, x0.w, x1.x, x1.y, x1.z, x1.w};
        #pragma unroll
        for (int e = 0; e < 8; e++) {
            unsigned short h = f2bf(xv[e]);
            float rem = xv[e] - BF2F(h);
            ah[ks][e] = (short)h;
            al[ks][e] = (short)f2bf(rem);
        }
    }

    f32x4 acc[8];
    #pragma unroll
    for (int nt = 0; nt < 8; nt++) acc[nt] = (f32x4){0.f, 0.f, 0.f, 0.f};

    #pragma unroll
    for (int nt = 0; nt < 8; nt++) {
        const size_t boff = (size_t)(nt * 16 + lm) * DF + kg * 8;
        #pragma unroll
        for (int ks = 0; ks < 4; ks++) {
            bf16x8 bh = *(const bf16x8*)(Wth + boff + ks * 32);
            bf16x8 bl = *(const bf16x8*)(Wtl + boff + ks * 32);
            acc[nt] = __builtin_amdgcn_mfma_f32_16x16x32_bf16(ah[ks], bh, acc[nt], 0, 0, 0);
            acc[nt] = __builtin_amdgcn_mfma_f32_16x16x32_bf16(al[ks], bh, acc[nt], 0, 0, 0);
            acc[nt] = __builtin_amdgcn_mfma_f32_16x16x32_bf16(ah[ks], bl, acc[nt], 0, 0, 0);
        }
    }

    // epilogue: D layout col=lm, row=kg*4+r
    const int rbase = blockIdx.x * GEMM_TILE_ROWS + w * 16 + kg * 4;
    #pragma unroll
    for (int r = 0; r < 4; r++) {
        const int ro = rbase + r;
        if (ro < n) {
            #pragma unroll
            for (int nt = 0; nt < 8; nt++) {
                const int col = nt * 16 + lm;
                float v = acc[nt][r];
                H[(size_t)ro * DF + col] = v;
                Hb[(size_t)ro * DF + col] = f2bf(v);
            }
        }
    }
}

// ---------------- aggregation: one wave per dst node, bf16 gathers ----------------
// out[i] = act( dinv[i]*sum coef[e]*Hb[src[e]] + dinv[i]^2*H[i] + b ); self-term fp32.
__global__ __launch_bounds__(256) void agg_kernel(const float* __restrict__ H, const unsigned short* __restrict__ Hb,
                                                  const int* __restrict__ rp, const int2* __restrict__ pk,
                                                  const float* __restrict__ dinv, const float* __restrict__ bias,
                                                  float* __restrict__ out, int n, int act) {
    const int lane = threadIdx.x & 63;
    const int sub = lane & 31;
    const int half = lane >> 5;
    const int i = blockIdx.x * 4 + (threadIdx.x >> 6);
    if (i >= n) return;
    const int start = rp[i];
    const int end = rp[i + 1];
    float ax = 0.f, ay = 0.f, az = 0.f, aw = 0.f;
    const unsigned short* __restrict__ Hbc = Hb + 4 * sub;
    for (int base = start; base < end; base += 64) {
        int cnt = end - base;
        if (cnt > 64) cnt = 64;
        int msrc = 0;
        float mdv = 0.f;
        if (lane < cnt) {  // coalesced 8B batch load of packed (src, coef)
            int2 pv = pk[base + lane];
            msrc = pv.x;
            mdv = __int_as_float(pv.y);
        }
        for (int j = 0; j < cnt; j += 16) {  // 16 edges per iter; 8 x 8B gathers in flight per half
            int e0 = j + half;               // halves take even/odd edges; pads have mdv==0
            int s[8]; float d[8];
            #pragma unroll
            for (int k = 0; k < 8; k++) {
                s[k] = __shfl(msrc, e0 + 2 * k);
                d[k] = __shfl(mdv, e0 + 2 * k);
            }
            ushort4 hb[8];
            #pragma unroll
            for (int k = 0; k < 8; k++) hb[k] = *(const ushort4*)(Hbc + (size_t)s[k] * DF);
            #pragma unroll
            for (int k = 0; k < 8; k++) {
                ax = fmaf(d[k], BF2F(hb[k].x), ax);
                ay = fmaf(d[k], BF2F(hb[k].y), ay);
                az = fmaf(d[k], BF2F(hb[k].z), az);
                aw = fmaf(d[k], BF2F(hb[k].w), aw);
            }
        }
    }
    // fold halves: lanes 0-31 += lanes 32-63
    ax += __shfl_down(ax, 32); ay += __shfl_down(ay, 32);
    az += __shfl_down(az, 32); aw += __shfl_down(aw, 32);
    if (half == 0) {
        float di = dinv[i];
        float dii = di * di;
        float4 hv = *(const float4*)(H + (size_t)i * DF + 4 * sub);   // self term fp32
        float4 bv = *(const float4*)(bias + 4 * sub);
        float ox = fmaf(di, ax, fmaf(dii, hv.x, bv.x));
        float oy = fmaf(di, ay, fmaf(dii, hv.y, bv.y));
        float oz = fmaf(di, az, fmaf(dii, hv.z, bv.z));
        float ow = fmaf(di, aw, fmaf(dii, hv.w, bv.w));
        if (act == 0) {  // ELU
            ox = ox > 0.f ? ox : expm1f(ox);
            oy = oy > 0.f ? oy : expm1f(oy);
            oz = oz > 0.f ? oz : expm1f(oz);
            ow = ow > 0.f ? ow : expm1f(ow);
        } else {  // ReLU
            ox = fmaxf(ox, 0.f); oy = fmaxf(oy, 0.f);
            oz = fmaxf(oz, 0.f); ow = fmaxf(ow, 0.f);
        }
        float4 ov; ov.x = ox; ov.y = oy; ov.z = oz; ov.w = ow;
        *(float4*)(out + (size_t)i * DF + 4 * sub) = ov;
    }
}

extern "C" void kernel_launch(void* const* d_in, const int* in_sizes, int n_in,
                              void* d_out, int out_size, void* d_ws, size_t ws_size,
                              hipStream_t stream) {
    const float* x  = (const float*)d_in[0];
    const float* W1 = (const float*)d_in[1];
    const float* b1 = (const float*)d_in[2];
    const float* W2 = (const float*)d_in[3];
    const float* b2 = (const float*)d_in[4];
    const float* W3 = (const float*)d_in[5];
    const float* b3 = (const float*)d_in[6];
    const float* W4 = (const float*)d_in[7];
    const float* b4 = (const float*)d_in[8];
    const int* ei1 = (const int*)d_in[9];
    const int* ei2 = (const int*)d_in[10];
    const int *src1 = ei1, *dst1 = ei1 + NE;
    const int *src2 = ei2, *dst2 = ei2 + NE;

    // ---- workspace carve-out (512B aligned), ~79 MB ----
    char* ws = (char*)d_ws;
    size_t off = 0;
    auto carve = [&](size_t bytes) -> void* {
        void* p = (void*)(ws + off);
        off += (bytes + 511) & ~(size_t)511;
        return p;
    };
    int* stgcnt = (int*)carve((size_t)16 * 4);
    int* subcnt = (int*)carve((size_t)256 * 4);
    size_t zero_bytes = off;
    int* cbase = (int*)carve((size_t)256 * 4);
    float* dinv1 = (float*)carve((size_t)NN * 4);
    float* dinv2 = (float*)carve((size_t)NN * 4);
    int* rp1 = (int*)carve((size_t)(NN + 1) * 4);
    int* rp2 = (int*)carve((size_t)(NN + 1) * 4);
    int2* pk1 = (int2*)carve((size_t)NE * 8);
    int2* pk2 = (int2*)carve((size_t)NE * 8);
    int2* stg = (int2*)carve((size_t)2 * NPART * STG_CAP * 8);   // 13.9 MB
    float* hpre = (float*)carve((size_t)NN * DF * 4);     // 25.6 MB
    float* hbuf = (float*)carve((size_t)NN * DF * 4);
    unsigned short* Wth = (unsigned short*)carve((size_t)4 * DF * DF * 2);  // 128 KB, [layer][n][k]
    unsigned short* Wtl = (unsigned short*)carve((size_t)4 * DF * DF * 2);  // 128 KB
    int2* stg2 = (int2*)hpre;                 // alias: stg2 dead before first gemm writes hpre
    unsigned short* hpreb = (unsigned short*)stg;  // alias: stg dead after subbin; 12.8MB <= 13.9MB

    float* outz  = (float*)d_out;
    float* outxr = (float*)d_out + (size_t)NN * DF;

    const int gGemm = (NN + GEMM_TILE_ROWS - 1) / GEMM_TILE_ROWS;   // 782
    const int gAgg = (NN + 3) / 4;
    const int gChunk = 2 * NPART * CHUNKS;                // 256 blocks
    const int WELEM = DF * DF;                            // 16384 per layer

    // ---- preprocessing: wprep -> bin -> subbin -> chunkscan -> histrp -> place ----
    hipMemsetAsync(stgcnt, 0, zero_bytes, stream);
    wprep_kernel<<<256, 256, 0, stream>>>(W1, W2, W3, W4, Wth, Wtl);
    bin_kernel<<<BIN_BLOCKS, 256, 0, stream>>>(src1, dst1, src2, dst2, stg, stgcnt);
    subbin_kernel<<<SUBBIN_BLOCKS, 256, 0, stream>>>(stg, stgcnt, stg2, subcnt);
    chunkscan_kernel<<<1, 256, 0, stream>>>(subcnt, cbase, rp1, rp2);
    histrp_kernel<<<gChunk, 256, 0, stream>>>(stg2, subcnt, cbase, rp1, dinv1, rp2, dinv2);
    place_kernel<<<gChunk, 256, 0, stream>>>(stg2, subcnt, rp1, rp2, dinv1, dinv2, pk1, pk2);

    // ---- layer 1: ELU(gcn(x, ei1, W1, b1)) -> hbuf ----
    gemm_mfma_kernel<<<gGemm, 256, 0, stream>>>(x, Wth, Wtl, hpre, hpreb, NN);
    agg_kernel<<<gAgg, 256, 0, stream>>>(hpre, hpreb, rp1, pk1, dinv1, b1, hbuf, NN, 0);
    // ---- layer 2: z = ELU(gcn(hbuf, ei2, W2, b2)) -> d_out ----
    gemm_mfma_kernel<<<gGemm, 256, 0, stream>>>(hbuf, Wth + WELEM, Wtl + WELEM, hpre, hpreb, NN);
    agg_kernel<<<gAgg, 256, 0, stream>>>(hpre, hpreb, rp2, pk2, dinv2, b2, outz, NN, 0);
    // ---- layer 3: ELU(gcn(z, ei1, W3, b3)) -> hbuf ----
    gemm_mfma_kernel<<<gGemm, 256, 0, stream>>>(outz, Wth + 2 * WELEM, Wtl + 2 * WELEM, hpre, hpreb, NN);
    agg_kernel<<<gAgg, 256, 0, stream>>>(hpre, hpreb, rp1, pk1, dinv1, b3, hbuf, NN, 0);
    // ---- layer 4: xr = ReLU(gcn(hbuf, ei2, W4, b4)) -> d_out[N*DF:] ----
    gemm_mfma_kernel<<<gGemm, 256, 0, stream>>>(hbuf, Wth + 3 * WELEM, Wtl + 3 * WELEM, hpre, hpreb, NN);
    agg_kernel<<<gAgg, 256, 0, stream>>>(hpre, hpreb, rp2, pk2, dinv2, b4, outxr, NN, 1);
}

// Round 2
// 395.481 us; speedup vs baseline: 1.2140x; 1.2091x over previous
//
#include <hip/hip_runtime.h>
#include <math.h>

#define NN 50000
#define NE 800000
#define DF 128
#define NPART 8
#define PART_SZ (NN / NPART)        // 6250, exact
#define STG_CAP 108544              // part segment: 100000 expected + slack
#define BIN_BLOCKS 512
#define BUCK_CAP 512
#define CHUNKS 16                   // chunks per part
#define CH_W 391                    // ceil(PART_SZ / CHUNKS); last chunk = 385
#define SUB_CAP 7680                // chunk mean 6256 edges, +18 sigma
#define SB_CAP 448                  // subbin bucket capacity
#define SB_TH 192                   // subbin flush threshold
#define SUBBIN_BLOCKS 512           // 16 segments x 32 slices
#define GEMM_BLK_ROWS 64            // rows per block (8 waves: 4 row-groups x 2 col-halves)

__device__ __forceinline__ unsigned short f2bf(float f) {  // round-to-nearest-even
    unsigned u = __float_as_uint(f);
    return (unsigned short)((u + 0x7FFF + ((u >> 16) & 1)) >> 16);
}
#define BF2F(u) __uint_as_float(((unsigned)(u)) << 16)

typedef __attribute__((ext_vector_type(8))) short bf16x8;
typedef __attribute__((ext_vector_type(4))) float f32x4;

// ---------------- phase 1: bin edges by dst-part into staging (r5-proven) ----------------
__global__ __launch_bounds__(256) void bin_kernel(const int* __restrict__ src1, const int* __restrict__ dst1,
                                                  const int* __restrict__ src2, const int* __restrict__ dst2,
                                                  int2* __restrict__ stg, int* __restrict__ stgcnt) {
    __shared__ int2 buck[NPART][BUCK_CAP];   // 32 KB
    __shared__ int bcnt[NPART];
    __shared__ int wbase[4][NPART];
    __shared__ int gbase[NPART];
    const int t = threadIdx.x, lane = t & 63, w = t >> 6;
    const int g = (blockIdx.x >= BIN_BLOCKS / 2) ? 1 : 0;
    const int bid = blockIdx.x - g * (BIN_BLOCKS / 2);
    const int nb = BIN_BLOCKS / 2;
    const int* __restrict__ srcv = g ? src2 : src1;
    const int* __restrict__ dstv = g ? dst2 : dst1;
    int2* __restrict__ stg_g = stg + (size_t)g * NPART * STG_CAP;
    int* __restrict__ cnt_g = stgcnt + g * NPART;
    if (t < NPART) bcnt[t] = 0;
    __syncthreads();
    for (int base = bid * 256; base < NE; base += nb * 256) {
        const int e = base + t;
        const bool v = (e < NE);
        int d = 0, s = 0, p = -1;
        if (v) { d = dstv[e]; s = srcv[e]; p = d / PART_SZ; }
        int rank = 0;
        const unsigned long long lt = (1ull << lane) - 1ull;
        int wc[NPART];
        #pragma unroll
        for (int q = 0; q < NPART; q++) {
            unsigned long long m = __ballot(p == q);
            wc[q] = (int)__popcll(m);
            if (p == q) rank = (int)__popcll(m & lt);
        }
        if (lane < NPART) wbase[w][lane] = wc[lane];
        __syncthreads();
        if (t < NPART) {
            int b = bcnt[t];
            int c0 = wbase[0][t], c1 = wbase[1][t], c2 = wbase[2][t], c3 = wbase[3][t];
            wbase[0][t] = b; wbase[1][t] = b + c0;
            wbase[2][t] = b + c0 + c1; wbase[3][t] = b + c0 + c1 + c2;
            bcnt[t] = b + c0 + c1 + c2 + c3;
        }
        __syncthreads();
        if (v) buck[p][wbase[w][p] + rank] = make_int2(s, d);
        __syncthreads();
        const bool last = (base + nb * 256) >= NE;
        if (t < NPART) {
            int c = bcnt[t];
            gbase[t] = (c >= 256 || (last && c > 0)) ? atomicAdd(&cnt_g[t], c) : -1;
        }
        __syncthreads();
        #pragma unroll
        for (int q = 0; q < NPART; q++) {
            int gb = gbase[q];
            if (gb >= 0) {
                int c = bcnt[q];
                for (int i = t; i < c; i += 256)
                    stg_g[(size_t)q * STG_CAP + gb + i] = buck[q][i];
            }
        }
        __syncthreads();
        if (t < NPART && gbase[t] >= 0) bcnt[t] = 0;
    }
}

// ---------------- phase 2: sub-bin part segments into 16 chunk sub-segments ----------------
__global__ __launch_bounds__(256) void subbin_kernel(const int2* __restrict__ stg, const int* __restrict__ stgcnt,
                                                     int2* __restrict__ stg2, int* __restrict__ subcnt) {
    __shared__ int2 buck[CHUNKS][SB_CAP];   // 56 KB
    __shared__ int bcnt[CHUNKS];
    __shared__ int wbase[4][CHUNKS];
    __shared__ int gbase[CHUNKS];
    const int t = threadIdx.x, lane = t & 63, w = t >> 6;
    const int p = blockIdx.x & 7;
    const int g = (blockIdx.x >> 3) & 1;
    const int slice = blockIdx.x >> 4;               // 0..31
    const int nsl = SUBBIN_BLOCKS / 16;              // 32
    const int m = stgcnt[g * NPART + p];
    const int2* __restrict__ seg = stg + ((size_t)g * NPART + p) * STG_CAP;
    const int segi0 = g * 128 + p * CHUNKS;
    int* __restrict__ cnt_c = subcnt + segi0;
    int2* __restrict__ out = stg2 + (size_t)segi0 * SUB_CAP;
    const int plo = p * PART_SZ;
    if (t < CHUNKS) bcnt[t] = 0;
    __syncthreads();
    for (int base = slice * 256; base < m; base += nsl * 256) {
        const int e = base + t;
        const bool v = (e < m);
        int2 ed = make_int2(0, 0);
        int q = -1;
        if (v) { ed = seg[e]; q = (ed.y - plo) / CH_W; }
        int rank = 0;
        const unsigned long long lt = (1ull << lane) - 1ull;
        int wc[CHUNKS];
        #pragma unroll
        for (int qq = 0; qq < CHUNKS; qq++) {
            unsigned long long mm = __ballot(q == qq);
            wc[qq] = (int)__popcll(mm);
            if (q == qq) rank = (int)__popcll(mm & lt);
        }
        if (lane < CHUNKS) wbase[w][lane] = wc[lane];
        __syncthreads();
        if (t < CHUNKS) {
            int b = bcnt[t];
            int c0 = wbase[0][t], c1 = wbase[1][t], c2 = wbase[2][t], c3 = wbase[3][t];
            wbase[0][t] = b; wbase[1][t] = b + c0;
            wbase[2][t] = b + c0 + c1; wbase[3][t] = b + c0 + c1 + c2;
            bcnt[t] = b + c0 + c1 + c2 + c3;
        }
        __syncthreads();
        if (v) buck[q][wbase[w][q] + rank] = ed;
        __syncthreads();
        const bool last = (base + nsl * 256) >= m;
        if (t < CHUNKS) {
            int c = bcnt[t];
            gbase[t] = (c >= SB_TH || (last && c > 0)) ? atomicAdd(&cnt_c[t], c) : -1;
        }
        __syncthreads();
        #pragma unroll
        for (int qq = 0; qq < CHUNKS; qq++) {
            int gb = gbase[qq];
            if (gb >= 0) {
                int c = bcnt[qq];
                for (int i = t; i < c; i += 256)
                    if (gb + i < SUB_CAP)
                        out[(size_t)qq * SUB_CAP + gb + i] = buck[qq][i];
            }
        }
        __syncthreads();
        if (t < CHUNKS && gbase[t] >= 0) bcnt[t] = 0;
    }
}

// ---------------- phase 3: scan the 256 chunk counts -> chunk bases ----------------
__global__ __launch_bounds__(256) void chunkscan_kernel(const int* __restrict__ subcnt, int* __restrict__ cbase,
                                                        int* __restrict__ rp1, int* __restrict__ rp2) {
    __shared__ int wtot[4];
    const int t = threadIdx.x, lane = t & 63, w = t >> 6;
    int v = subcnt[t];
    int x = v;
    #pragma unroll
    for (int off = 1; off < 64; off <<= 1) { int y = __shfl_up(x, off); if (lane >= off) x += y; }
    if (lane == 63) wtot[w] = x;
    __syncthreads();
    int add = (w == 1) ? wtot[0] : ((w == 3) ? wtot[2] : 0);
    cbase[t] = x - v + add;
    if (t == 0) { rp1[NN] = NE; rp2[NN] = NE; }
}

// ---------------- phase 4: per-chunk degree hist + LDS scan -> rp + dinv ----------------
__global__ __launch_bounds__(256) void histrp_kernel(const int2* __restrict__ stg2, const int* __restrict__ subcnt,
                                                     const int* __restrict__ cbase,
                                                     int* __restrict__ rp1, float* __restrict__ dinv1,
                                                     int* __restrict__ rp2, float* __restrict__ dinv2) {
    __shared__ int deg[512];
    const int t = threadIdx.x;
    const int p = blockIdx.x & 7, c = (blockIdx.x >> 3) & 15, g = blockIdx.x >> 7;
    const int segi = g * 128 + p * CHUNKS + c;
    int m = subcnt[segi];
    if (m > SUB_CAP) m = SUB_CAP;
    const int2* __restrict__ seg = stg2 + (size_t)segi * SUB_CAP;
    int* __restrict__ rp = g ? rp2 : rp1;
    float* __restrict__ dinv = g ? dinv2 : dinv1;
    const int lo = p * PART_SZ + c * CH_W;
    int hi = lo + CH_W;
    const int pend = (p + 1) * PART_SZ;
    if (hi > pend) hi = pend;
    const int nw = hi - lo;
    deg[t] = 0; deg[t + 256] = 0;
    __syncthreads();
    for (int i = t; i < m; i += 256) atomicAdd(&deg[seg[i].y - lo], 1);
    __syncthreads();
    if (t < nw) dinv[lo + t] = rsqrtf((float)deg[t] + 1.0f);
    if (t + 256 < nw) dinv[lo + t + 256] = rsqrtf((float)deg[t + 256] + 1.0f);
    #pragma unroll
    for (int off = 1; off < 512; off <<= 1) {
        int v0 = (t >= off) ? deg[t - off] : 0;
        int v1 = (t + 256 >= off) ? deg[t + 256 - off] : 0;
        __syncthreads();
        deg[t] += v0; deg[t + 256] += v1;
        __syncthreads();
    }
    const int base = cbase[segi];
    if (t < nw) rp[lo + t] = base + (t ? deg[t - 1] : 0);
    if (t + 256 < nw) rp[lo + t + 256] = base + deg[t + 256 - 1];
}

// ---------------- phase 5: LDS-sorted placement from OWN sub-segment ----------------
__global__ __launch_bounds__(256) void place_kernel(const int2* __restrict__ stg2, const int* __restrict__ subcnt,
                                                    const int* __restrict__ rp1, const int* __restrict__ rp2,
                                                    const float* __restrict__ dinv1, const float* __restrict__ dinv2,
                                                    int2* __restrict__ pk1, int2* __restrict__ pk2) {
    __shared__ int2 sorted[SUB_CAP];    // 60 KB
    __shared__ int fill[CH_W];
    __shared__ int rps[CH_W + 1];
    const int t = threadIdx.x;
    const int p = blockIdx.x & 7, c = (blockIdx.x >> 3) & 15, g = blockIdx.x >> 7;
    const int segi = g * 128 + p * CHUNKS + c;
    int m = subcnt[segi];
    if (m > SUB_CAP) m = SUB_CAP;
    const int2* __restrict__ seg = stg2 + (size_t)segi * SUB_CAP;
    const int* __restrict__ rp = g ? rp2 : rp1;
    const float* __restrict__ dinv = g ? dinv2 : dinv1;
    int2* __restrict__ pk = g ? pk2 : pk1;
    const int lo = p * PART_SZ + c * CH_W;
    int hi = lo + CH_W;
    const int pend = (p + 1) * PART_SZ;
    if (hi > pend) hi = pend;
    const int nw = hi - lo;
    for (int i = t; i < nw; i += 256) { fill[i] = 0; rps[i] = rp[lo + i]; }
    if (t == 0) rps[nw] = rp[hi];
    __syncthreads();
    const int segbase = rps[0];
    const int total = rps[nw] - segbase;
    for (int i = t; i < m; i += 256) {
        int2 e = seg[i];
        int dl = e.y - lo;
        int lp = rps[dl] - segbase + atomicAdd(&fill[dl], 1);
        if (lp < SUB_CAP)
            sorted[lp] = make_int2(e.x, __float_as_int(dinv[e.x]));
    }
    __syncthreads();
    for (int i = t; i < total; i += 256)
        pk[segbase + i] = sorted[i];
}

// ---------------- W prep: emit W as bf16 hi/lo in EXACT MFMA fragment order ----------------
// Per layer, 32768 shorts = 64 KB laid out [hl(2)][colhalf(2)][grp=nt*4+ks(16)][lane(64)][e(8)].
// Fragment (hl,h,nt,ks,lane=(kg,lm),e) = bf16 of W^T[col=h*64+nt*16+lm][k=ks*32+kg*8+e].
// GEMM stages this linearly into LDS; every ds_read_b128 is lane-linear 1024B (conflict-free).
__global__ __launch_bounds__(256) void wprep_kernel(const float* __restrict__ W1, const float* __restrict__ W2,
                                                    const float* __restrict__ W3, const float* __restrict__ W4,
                                                    unsigned short* __restrict__ Wpk) {
    const int u = blockIdx.x * 256 + threadIdx.x;   // 0..131071
    const int layer = u >> 15;
    const int r = u & 32767;
    const int fidx = r >> 3, e = r & 7;
    const int lane = fidx & 63;
    const int q = fidx >> 6;             // 0..63
    const int grp = q & 15, hh = q >> 4; // hh = hl*2 + h
    const int hl = hh >> 1, h = hh & 1;
    const int nt = grp >> 2, ks = grp & 3;
    const int kg = lane >> 4, lm = lane & 15;
    const int ncol = h * 64 + nt * 16 + lm;
    const int kk = ks * 32 + kg * 8 + e;
    const float* __restrict__ W = layer == 0 ? W1 : layer == 1 ? W2 : layer == 2 ? W3 : W4;
    float v = W[kk * DF + ncol];
    unsigned short hi = f2bf(v);
    Wpk[u] = hl ? f2bf(v - BF2F(hi)) : hi;
}

// ---------------- H = X @ W via bf16x3-split MFMA, W fragments staged in LDS ----------------
// 8 waves: w = rg(4) x h(2). Wave computes rows rb..rb+15 x cols h*64..h*64+63 (4 nt tiles).
// A-frag: m=lm, k=kg*8+e (per 32-k block ks). D-frag: col=lm, row=kg*4+r (verified layout).
// acc = ah*bh; accl = al*bh + ah*bl  (split accumulators for shorter MFMA dep chains).
__global__ __launch_bounds__(512, 4) void gemm_mfma_kernel(const float* __restrict__ X,
                                                           const unsigned short* __restrict__ Wpk,
                                                           unsigned short* __restrict__ Hhi,
                                                           unsigned short* __restrict__ Hlo, int n) {
    __shared__ __align__(16) unsigned short smem[32768];   // 64 KB, mirrors Wpk layer layout
    const int t = threadIdx.x;
    const int lane = t & 63, w = t >> 6;
    const int h = w >> 2, rg = w & 3;
    const int lm = lane & 15, kg = lane >> 4;
    const int rb = blockIdx.x * GEMM_BLK_ROWS + rg * 16;
    const int row = rb + lm;

    // stage permuted W (hi+lo) into LDS: 4096 x 16B linear copy
    {
        const float4* __restrict__ g4 = (const float4*)Wpk;
        float4* s4 = (float4*)smem;
        #pragma unroll
        for (int i = 0; i < 8; i++) s4[t + 512 * i] = g4[t + 512 * i];
    }

    // load + split A fragments (read X once; hi/lo bf16 in registers) while stage lands
    bf16x8 ah[4], al[4];
    #pragma unroll
    for (int ks = 0; ks < 4; ks++) {
        float4 x0 = make_float4(0.f, 0.f, 0.f, 0.f), x1 = x0;
        if (row < n) {
            const float* xp = X + (size_t)row * DF + ks * 32 + kg * 8;
            x0 = *(const float4*)xp;
            x1 = *(const float4*)(xp + 4);
        }
        float xv[8] = {x0.x, x0.y, x0.z, x0.w, x1.x, x1.y, x1.z, x1.w};
        #pragma unroll
        for (int e = 0; e < 8; e++) {
            unsigned short hi = f2bf(xv[e]);
            float rem = xv[e] - BF2F(hi);
            ah[ks][e] = (short)hi;
            al[ks][e] = (short)f2bf(rem);
        }
    }
    __syncthreads();

    f32x4 acc[4], accl[4];
    #pragma unroll
    for (int nt = 0; nt < 4; nt++) { acc[nt] = (f32x4){0.f, 0.f, 0.f, 0.f}; accl[nt] = acc[nt]; }

    const unsigned short* __restrict__ bhb = smem + ((size_t)(h * 16) * 64 + lane) * 8;
    const unsigned short* __restrict__ blb = smem + ((size_t)((2 + h) * 16) * 64 + lane) * 8;
    #pragma unroll
    for (int nt = 0; nt < 4; nt++) {
        #pragma unroll
        for (int ks = 0; ks < 4; ks++) {
            const int grp = nt * 4 + ks;
            bf16x8 bh = *(const bf16x8*)(bhb + (size_t)grp * 512);
            bf16x8 bl = *(const bf16x8*)(blb + (size_t)grp * 512);
            acc[nt]  = __builtin_amdgcn_mfma_f32_16x16x32_bf16(ah[ks], bh, acc[nt], 0, 0, 0);
            accl[nt] = __builtin_amdgcn_mfma_f32_16x16x32_bf16(al[ks], bh, accl[nt], 0, 0, 0);
            accl[nt] = __builtin_amdgcn_mfma_f32_16x16x32_bf16(ah[ks], bl, accl[nt], 0, 0, 0);
        }
    }

    // epilogue: D layout col=lm, row=kg*4+r; write bf16 hi + bf16 lo (no fp32 H)
    const int rwb = rb + kg * 4;
    #pragma unroll
    for (int r = 0; r < 4; r++) {
        const int ro = rwb + r;
        if (ro < n) {
            #pragma unroll
            for (int nt = 0; nt < 4; nt++) {
                const int col = h * 64 + nt * 16 + lm;
                float v = acc[nt][r] + accl[nt][r];
                unsigned short hi = f2bf(v);
                Hhi[(size_t)ro * DF + col] = hi;
                Hlo[(size_t)ro * DF + col] = f2bf(v - BF2F(hi));
            }
        }
    }
}

// ---------------- aggregation: one wave per dst node, bf16 gathers ----------------
// out[i] = act( dinv[i]*sum coef[e]*Hhi[src[e]] + dinv[i]^2*(Hhi[i]+Hlo[i]) + b )
__global__ __launch_bounds__(256) void agg_kernel(const unsigned short* __restrict__ Hhi,
                                                  const unsigned short* __restrict__ Hlo,
                                                  const int* __restrict__ rp, const int2* __restrict__ pk,
                                                  const float* __restrict__ dinv, const float* __restrict__ bias,
                                                  float* __restrict__ out, int n, int act) {
    const int lane = threadIdx.x & 63;
    const int sub = lane & 31;
    const int half = lane >> 5;
    const int i = blockIdx.x * 4 + (threadIdx.x >> 6);
    if (i >= n) return;
    const int start = rp[i];
    const int end = rp[i + 1];
    float ax = 0.f, ay = 0.f, az = 0.f, aw = 0.f;
    const unsigned short* __restrict__ Hbc = Hhi + 4 * sub;
    for (int base = start; base < end; base += 64) {
        int cnt = end - base;
        if (cnt > 64) cnt = 64;
        int msrc = 0;
        float mdv = 0.f;
        if (lane < cnt) {  // coalesced 8B batch load of packed (src, coef)
            int2 pv = pk[base + lane];
            msrc = pv.x;
            mdv = __int_as_float(pv.y);
        }
        for (int j = 0; j < cnt; j += 16) {  // 16 edges per iter; 8 x 8B gathers in flight per half
            int e0 = j + half;               // halves take even/odd edges; pads have mdv==0
            int s[8]; float d[8];
            #pragma unroll
            for (int k = 0; k < 8; k++) {
                s[k] = __shfl(msrc, e0 + 2 * k);
                d[k] = __shfl(mdv, e0 + 2 * k);
            }
            ushort4 hb[8];
            #pragma unroll
            for (int k = 0; k < 8; k++) hb[k] = *(const ushort4*)(Hbc + (size_t)s[k] * DF);
            #pragma unroll
            for (int k = 0; k < 8; k++) {
                ax = fmaf(d[k], BF2F(hb[k].x), ax);
                ay = fmaf(d[k], BF2F(hb[k].y), ay);
                az = fmaf(d[k], BF2F(hb[k].z), az);
                aw = fmaf(d[k], BF2F(hb[k].w), aw);
            }
        }
    }
    // fold halves: lanes 0-31 += lanes 32-63
    ax += __shfl_down(ax, 32); ay += __shfl_down(ay, 32);
    az += __shfl_down(az, 32); aw += __shfl_down(aw, 32);
    if (half == 0) {
        float di = dinv[i];
        float dii = di * di;
        ushort4 hh4 = *(const ushort4*)(Hhi + (size_t)i * DF + 4 * sub);   // self term hi+lo ~ fp32
        ushort4 hl4 = *(const ushort4*)(Hlo + (size_t)i * DF + 4 * sub);
        float4 bv = *(const float4*)(bias + 4 * sub);
        float hx = BF2F(hh4.x) + BF2F(hl4.x);
        float hy = BF2F(hh4.y) + BF2F(hl4.y);
        float hz = BF2F(hh4.z) + BF2F(hl4.z);
        float hw = BF2F(hh4.w) + BF2F(hl4.w);
        float ox = fmaf(di, ax, fmaf(dii, hx, bv.x));
        float oy = fmaf(di, ay, fmaf(dii, hy, bv.y));
        float oz = fmaf(di, az, fmaf(dii, hz, bv.z));
        float ow = fmaf(di, aw, fmaf(dii, hw, bv.w));
        if (act == 0) {  // ELU
            ox = ox > 0.f ? ox : expm1f(ox);
            oy = oy > 0.f ? oy : expm1f(oy);
            oz = oz > 0.f ? oz : expm1f(oz);
            ow = ow > 0.f ? ow : expm1f(ow);
        } else {  // ReLU
            ox = fmaxf(ox, 0.f); oy = fmaxf(oy, 0.f);
            oz = fmaxf(oz, 0.f); ow = fmaxf(ow, 0.f);
        }
        float4 ov; ov.x = ox; ov.y = oy; ov.z = oz; ov.w = ow;
        *(float4*)(out + (size_t)i * DF + 4 * sub) = ov;
    }
}

extern "C" void kernel_launch(void* const* d_in, const int* in_sizes, int n_in,
                              void* d_out, int out_size, void* d_ws, size_t ws_size,
                              hipStream_t stream) {
    const float* x  = (const float*)d_in[0];
    const float* W1 = (const float*)d_in[1];
    const float* b1 = (const float*)d_in[2];
    const float* W2 = (const float*)d_in[3];
    const float* b2 = (const float*)d_in[4];
    const float* W3 = (const float*)d_in[5];
    const float* b3 = (const float*)d_in[6];
    const float* W4 = (const float*)d_in[7];
    const float* b4 = (const float*)d_in[8];
    const int* ei1 = (const int*)d_in[9];
    const int* ei2 = (const int*)d_in[10];
    const int *src1 = ei1, *dst1 = ei1 + NE;
    const int *src2 = ei2, *dst2 = ei2 + NE;

    // ---- workspace carve-out (512B aligned) ----
    char* ws = (char*)d_ws;
    size_t off = 0;
    auto carve = [&](size_t bytes) -> void* {
        void* p = (void*)(ws + off);
        off += (bytes + 511) & ~(size_t)511;
        return p;
    };
    int* stgcnt = (int*)carve((size_t)16 * 4);
    int* subcnt = (int*)carve((size_t)256 * 4);
    size_t zero_bytes = off;
    int* cbase = (int*)carve((size_t)256 * 4);
    float* dinv1 = (float*)carve((size_t)NN * 4);
    float* dinv2 = (float*)carve((size_t)NN * 4);
    int* rp1 = (int*)carve((size_t)(NN + 1) * 4);
    int* rp2 = (int*)carve((size_t)(NN + 1) * 4);
    int2* pk1 = (int2*)carve((size_t)NE * 8);
    int2* pk2 = (int2*)carve((size_t)NE * 8);
    int2* stg = (int2*)carve((size_t)2 * NPART * STG_CAP * 8);   // 13.9 MB
    float* hpre = (float*)carve((size_t)NN * DF * 4);            // 25.6 MB
    float* hbuf = (float*)carve((size_t)NN * DF * 4);
    unsigned short* Wpk = (unsigned short*)carve((size_t)4 * 32768 * 2);  // 256 KB, fragment-ordered
    int2* stg2 = (int2*)hpre;                       // alias: stg2 (15.7MB) dead before first gemm writes Hlo
    unsigned short* Hhi = (unsigned short*)stg;     // alias: stg dead after subbin; 12.8MB <= 13.9MB
    unsigned short* Hlo = (unsigned short*)hpre;    // alias: 12.8MB <= 25.6MB

    float* outz  = (float*)d_out;
    float* outxr = (float*)d_out + (size_t)NN * DF;

    const int gGemm = (NN + GEMM_BLK_ROWS - 1) / GEMM_BLK_ROWS;   // 782
    const int gAgg = (NN + 3) / 4;
    const int gChunk = 2 * NPART * CHUNKS;                // 256 blocks
    const int WL = 32768;                                 // Wpk shorts per layer

    // ---- preprocessing: wprep -> bin -> subbin -> chunkscan -> histrp -> place ----
    hipMemsetAsync(stgcnt, 0, zero_bytes, stream);
    wprep_kernel<<<512, 256, 0, stream>>>(W1, W2, W3, W4, Wpk);
    bin_kernel<<<BIN_BLOCKS, 256, 0, stream>>>(src1, dst1, src2, dst2, stg, stgcnt);
    subbin_kernel<<<SUBBIN_BLOCKS, 256, 0, stream>>>(stg, stgcnt, stg2, subcnt);
    chunkscan_kernel<<<1, 256, 0, stream>>>(subcnt, cbase, rp1, rp2);
    histrp_kernel<<<gChunk, 256, 0, stream>>>(stg2, subcnt, cbase, rp1, dinv1, rp2, dinv2);
    place_kernel<<<gChunk, 256, 0, stream>>>(stg2, subcnt, rp1, rp2, dinv1, dinv2, pk1, pk2);

    // ---- layer 1: ELU(gcn(x, ei1, W1, b1)) -> hbuf ----
    gemm_mfma_kernel<<<gGemm, 512, 0, stream>>>(x, Wpk, Hhi, Hlo, NN);
    agg_kernel<<<gAgg, 256, 0, stream>>>(Hhi, Hlo, rp1, pk1, dinv1, b1, hbuf, NN, 0);
    // ---- layer 2: z = ELU(gcn(hbuf, ei2, W2, b2)) -> d_out ----
    gemm_mfma_kernel<<<gGemm, 512, 0, stream>>>(hbuf, Wpk + WL, Hhi, Hlo, NN);
    agg_kernel<<<gAgg, 256, 0, stream>>>(Hhi, Hlo, rp2, pk2, dinv2, b2, outz, NN, 0);
    // ---- layer 3: ELU(gcn(z, ei1, W3, b3)) -> hbuf ----
    gemm_mfma_kernel<<<gGemm, 512, 0, stream>>>(outz, Wpk + 2 * WL, Hhi, Hlo, NN);
    agg_kernel<<<gAgg, 256, 0, stream>>>(Hhi, Hlo, rp1, pk1, dinv1, b3, hbuf, NN, 0);
    // ---- layer 4: xr = ReLU(gcn(hbuf, ei2, W4, b4)) -> d_out[N*DF:] ----
    gemm_mfma_kernel<<<gGemm, 512, 0, stream>>>(hbuf, Wpk + 3 * WL, Hhi, Hlo, NN);
    agg_kernel<<<gAgg, 256, 0, stream>>>(Hhi, Hlo, rp2, pk2, dinv2, b4, outxr, NN, 1);
}